// Round 8
// baseline (192.511 us; speedup 1.0000x reference)
//
#include <hip/hip_runtime.h>
#include <hip/hip_bf16.h>

using u16 = unsigned short;
typedef __attribute__((ext_vector_type(8))) short short8v;
typedef __attribute__((ext_vector_type(4))) float f32x4;

#define MFMA16(a, b, c) __builtin_amdgcn_mfma_f32_16x16x32_bf16((a), (b), (c), 0, 0, 0)

#define GLOAD16(g, l) __builtin_amdgcn_global_load_lds(                       \
    (const __attribute__((address_space(1))) void*)(const void*)(g),          \
    (__attribute__((address_space(3))) void*)(void*)(l), 16, 0, 0)

static __device__ __forceinline__ u16 f2bf(float x) {
  __hip_bfloat16 h = __float2bfloat16(x);
  return __builtin_bit_cast(u16, h);
}

// cast the two weight matrices (1M elems each)
__global__ __launch_bounds__(256) void cast2_f32_bf16(const float* __restrict__ a, u16* __restrict__ da,
                                                      const float* __restrict__ b, u16* __restrict__ db) {
  int bid = blockIdx.x;
  const float* s; u16* d; int i;
  if (bid < 1024) { s = a; d = da; i = bid; }
  else            { s = b; d = db; i = bid - 1024; }
  int idx = (i * 256 + threadIdx.x) * 4;
  float4 v = *reinterpret_cast<const float4*>(s + idx);
  ushort4 o;
  o.x = f2bf(v.x); o.y = f2bf(v.y); o.z = f2bf(v.z); o.w = f2bf(v.w);
  *reinterpret_cast<ushort4*>(d + idx) = o;
}

// out = p0 + p1 (fp32), float4-vectorized
__global__ __launch_bounds__(256) void reduce2(const float* __restrict__ p0,
                                               const float* __restrict__ p1,
                                               float* __restrict__ out) {
  int i = (blockIdx.x * 256 + threadIdx.x) * 4;
  float4 a = *reinterpret_cast<const float4*>(p0 + i);
  float4 b = *reinterpret_cast<const float4*>(p1 + i);
  float4 o = {a.x + b.x, a.y + b.y, a.z + b.z, a.w + b.w};
  *reinterpret_cast<float4*>(out + i) = o;
}

// C[M,N] fp32 = A[M,K] bf16 @ Bt[N,K]^T, SPLIT-K over blockIdx.z (each z does
// K2 of the K dim, writing partial C at C + z*M*N). BM=64 BN=128 BK=32,
// 4 waves (2x2). Depth-2 counted-vmcnt pipeline (T3+T4), 4 LDS buffers.
__global__ __launch_bounds__(256) void gemm_bt(const u16* __restrict__ A,
                                               const u16* __restrict__ Bt,
                                               float* __restrict__ C,
                                               int M, int N, int K, int K2) {
  __shared__ u16 As[4][64 * 32];
  __shared__ u16 Bs[4][128 * 32];
  unsigned flat = blockIdx.y * gridDim.x + blockIdx.x;
  unsigned nwg = gridDim.x * gridDim.y;
  unsigned swz = (flat & 7) * (nwg >> 3) + (flat >> 3);  // nwg % 8 == 0
  int bm = swz % gridDim.x, bn = swz / gridDim.x;
  int z = blockIdx.z;
  int tid = threadIdx.x;
  int wid = tid >> 6, l = tid & 63, lr = l & 15, lg = l >> 4;
  int wr = wid >> 1, wc = wid & 1;

  int srow = l >> 2, scol = (l & 3) * 8;
  const u16* Ag  = A  + (size_t)(bm * 64 + wid * 16 + srow) * K + z * K2 + scol;
  const u16* Bg0 = Bt + (size_t)(bn * 128 + wid * 32 + srow) * K + z * K2 + scol;
  const u16* Bg1 = Bg0 + (size_t)16 * K;
  C += (size_t)z * M * N;

  f32x4 acc[2][4];
#pragma unroll
  for (int m = 0; m < 2; m++)
#pragma unroll
    for (int n = 0; n < 4; n++) acc[m][n] = (f32x4){0.f, 0.f, 0.f, 0.f};

  const int NT = K2 >> 5;

#pragma unroll
  for (int t = 0; t < 2; t++) {
    GLOAD16(Ag + t * 32, &As[t][wid * 512]);
    GLOAD16(Bg0 + t * 32, &Bs[t][wid * 1024]);
    GLOAD16(Bg1 + t * 32, &Bs[t][wid * 1024 + 512]);
  }

  for (int t = 0; t < NT; t++) {
    int cur = t & 3;
    if (t + 2 < NT) {
      int nb = (t + 2) & 3;
      int ko = (t + 2) * 32;
      GLOAD16(Ag + ko, &As[nb][wid * 512]);
      GLOAD16(Bg0 + ko, &Bs[nb][wid * 1024]);
      GLOAD16(Bg1 + ko, &Bs[nb][wid * 1024 + 512]);
    }
    if (t + 2 < NT)      asm volatile("s_waitcnt vmcnt(6)" ::: "memory");
    else if (t + 1 < NT) asm volatile("s_waitcnt vmcnt(3)" ::: "memory");
    else                 asm volatile("s_waitcnt vmcnt(0)" ::: "memory");
    __builtin_amdgcn_s_barrier();

    short8v af[2], bfr[4];
#pragma unroll
    for (int m = 0; m < 2; m++)
      af[m] = *reinterpret_cast<const short8v*>(&As[cur][(wr * 32 + m * 16 + lr) * 32 + lg * 8]);
#pragma unroll
    for (int n = 0; n < 4; n++)
      bfr[n] = *reinterpret_cast<const short8v*>(&Bs[cur][(wc * 64 + n * 16 + lr) * 32 + lg * 8]);
    asm volatile("s_waitcnt lgkmcnt(0)" ::: "memory");
    __builtin_amdgcn_sched_barrier(0);  // pin MFMAs below the wait (rule #18)
    __builtin_amdgcn_s_setprio(1);
#pragma unroll
    for (int m = 0; m < 2; m++)
#pragma unroll
      for (int n = 0; n < 4; n++) acc[m][n] = MFMA16(af[m], bfr[n], acc[m][n]);
    __builtin_amdgcn_s_setprio(0);
  }

#pragma unroll
  for (int m = 0; m < 2; m++)
#pragma unroll
    for (int n = 0; n < 4; n++)
#pragma unroll
      for (int r = 0; r < 4; r++) {
        int row = bm * 64 + wr * 32 + m * 16 + lg * 4 + r;
        int col = bn * 128 + wc * 64 + n * 16 + lr;
        C[(size_t)row * N + col] = acc[m][n][r];
      }
}

// fused x cast + rotary + rms_norm for q: one wave per (b,t,h) row of 64.
// src x (B,T,H,D) fp32 -> xbf (same layout, bf16) AND q (B,H,T,D) bf16 scaled.
__global__ __launch_bounds__(256) void rope_rms_x(const float* __restrict__ src,
                                                  u16* __restrict__ xbf,
                                                  u16* __restrict__ qdst,
                                                  const float* __restrict__ cosp,
                                                  const float* __restrict__ sinp,
                                                  float scale) {
  int R = blockIdx.x * 4 + (threadIdx.x >> 6);  // R = (b*T + t)*H + h
  int l = threadIdx.x & 63;
  int h = R & 15;
  int bt = R >> 4;
  int t = bt & 2047, b = bt >> 11;

  float v = src[((size_t)R << 6) + l];
  xbf[((size_t)R << 6) + l] = f2bf(v);
  float p = __shfl_xor(v, 32);
  float c = cosp[(t << 5) + (l & 31)];
  float s = sinp[(t << 5) + (l & 31)];
  float r = v * c + ((l < 32) ? p * s : -p * s);
  float sq = r * r;
  sq += __shfl_xor(sq, 32);
  sq += __shfl_xor(sq, 16);
  sq += __shfl_xor(sq, 8);
  sq += __shfl_xor(sq, 4);
  sq += __shfl_xor(sq, 2);
  sq += __shfl_xor(sq, 1);
  float inv = rsqrtf(sq * (1.0f / 64.0f) + 1.1920928955078125e-07f) * scale;
  qdst[((((size_t)b * 16 + h) * 2048 + t) << 6) + l] = f2bf(r * inv);
}

// fused split-K sum + rotary + rms_norm for kv, writing BOTH (B,H,T,D) and
// transposed (B,H,D,T). grid (T/64, BH); 4 waves; wave w: t-rows w*16..+15.
__global__ __launch_bounds__(256) void rope_rms_kv(const float* __restrict__ srcP0,
                                                   const float* __restrict__ srcP1,
                                                   u16* __restrict__ dst,
                                                   u16* __restrict__ dstT,
                                                   const float* __restrict__ cosp,
                                                   const float* __restrict__ sinp) {
  __shared__ u16 Ld[64][72];
  int t0 = blockIdx.x << 6;
  int bh = blockIdx.y;
  int b = bh >> 4, h = bh & 15;
  int tid = threadIdx.x;
  int w = tid >> 6, l = tid & 63;

  for (int i = 0; i < 16; i++) {
    int tt = w * 16 + i;
    int t = t0 + tt;
    size_t idx = ((((size_t)b * 2048 + t) * 16 + h) << 6) + l;
    float v = srcP0[idx] + srcP1[idx];
    float p = __shfl_xor(v, 32);
    float cl = cosp[(t << 5) + (l & 31)];
    float sl = sinp[(t << 5) + (l & 31)];
    float r = v * cl + ((l < 32) ? p * sl : -p * sl);
    float sq = r * r;
    sq += __shfl_xor(sq, 32);
    sq += __shfl_xor(sq, 16);
    sq += __shfl_xor(sq, 8);
    sq += __shfl_xor(sq, 4);
    sq += __shfl_xor(sq, 2);
    sq += __shfl_xor(sq, 1);
    float inv = rsqrtf(sq * (1.0f / 64.0f) + 1.1920928955078125e-07f);
    u16 val = f2bf(r * inv);
    dst[(((size_t)bh * 2048 + t) << 6) + l] = val;
    Ld[tt][l] = val;
  }
  __syncthreads();
#pragma unroll
  for (int i = 0; i < 2; i++) {
    int c = tid + i * 256, dr = c >> 3, sg = c & 7;
    short8v v;
#pragma unroll
    for (int j = 0; j < 8; j++) v[j] = (short)Ld[sg * 8 + j][dr];
    *reinterpret_cast<short8v*>(dstT + ((size_t)bh * 64 + dr) * 2048 + t0 + sg * 8) = v;
  }
}

// sliding-window flash attention. Q: (B,H,T,D) bf16 PRE-SCALED by 0.125*log2e;
// KV: (B,H,T,D); KVt: (B,H,D,T). O: (B,T,H*D) bf16.
// NO online max: |s| <= 11.6 (rms-normed rows), so p = exp2(s-12) <= 1 and the
// final division cancels the fixed offset -> numerically identical softmax.
__global__ __launch_bounds__(256) void attn_swa(const u16* __restrict__ Q,
                                                const u16* __restrict__ KV,
                                                const u16* __restrict__ KVt,
                                                u16* __restrict__ O,
                                                const int* __restrict__ winp) {
  const int T = 2048;
  int bid = blockIdx.x;
  int bh = bid & 31;
  int qi = 31 - (bid >> 5);
  int q0 = qi << 6;
  int b = bh >> 4, h = bh & 15;
  int W = *winp;
  int tid = threadIdx.x;
  int wid = tid >> 6, l = tid & 63, lr = l & 15, lg = l >> 4;

  __shared__ u16 Kl[64][72];
  __shared__ u16 Vt[64][72];
  __shared__ u16 Pl[4][16][72];

  const u16* Qb = Q + (((size_t)bh * T + q0 + wid * 16 + lr) << 6);
  short8v aq0 = *reinterpret_cast<const short8v*>(Qb + lg * 8);
  short8v aq1 = *reinterpret_cast<const short8v*>(Qb + 32 + lg * 8);

  const short one_bf = (short)0x3F80;
  short8v vones = {one_bf, one_bf, one_bf, one_bf, one_bf, one_bf, one_bf, one_bf};

  float l_run[4];
  f32x4 oacc[4];
#pragma unroll
  for (int r = 0; r < 4; r++) l_run[r] = 0.f;
#pragma unroll
  for (int dt = 0; dt < 4; dt++) oacc[dt] = (f32x4){0.f, 0.f, 0.f, 0.f};

  int lo = q0 - W;
  if (lo < 0) lo = 0;
  lo &= ~63;

  const u16* KVbh  = KV + (((size_t)bh * T) << 6);
  const u16* KVtbh = KVt + ((size_t)bh << 6) * T;
  int r8 = tid >> 3, sg = tid & 7;

  short8v vK0 = *reinterpret_cast<const short8v*>(KVbh + ((size_t)(lo + r8) << 6) + sg * 8);
  short8v vK1 = *reinterpret_cast<const short8v*>(KVbh + ((size_t)(lo + r8 + 32) << 6) + sg * 8);
  short8v vV0 = *reinterpret_cast<const short8v*>(KVtbh + (size_t)r8 * T + lo + sg * 8);
  short8v vV1 = *reinterpret_cast<const short8v*>(KVtbh + (size_t)(r8 + 32) * T + lo + sg * 8);

  for (int kt = lo; kt <= q0; kt += 64) {
    __syncthreads();
    *reinterpret_cast<short8v*>(&Kl[r8][sg * 8]) = vK0;
    *reinterpret_cast<short8v*>(&Kl[r8 + 32][sg * 8]) = vK1;
    *reinterpret_cast<short8v*>(&Vt[r8][sg * 8]) = vV0;
    *reinterpret_cast<short8v*>(&Vt[r8 + 32][sg * 8]) = vV1;
    __syncthreads();
    if (kt < q0) {
      vK0 = *reinterpret_cast<const short8v*>(KVbh + ((size_t)(kt + 64 + r8) << 6) + sg * 8);
      vK1 = *reinterpret_cast<const short8v*>(KVbh + ((size_t)(kt + 64 + r8 + 32) << 6) + sg * 8);
      vV0 = *reinterpret_cast<const short8v*>(KVtbh + (size_t)r8 * T + kt + 64 + sg * 8);
      vV1 = *reinterpret_cast<const short8v*>(KVtbh + (size_t)(r8 + 32) * T + kt + 64 + sg * 8);
    }

    f32x4 s[4];
#pragma unroll
    for (int nt = 0; nt < 4; nt++) {
      s[nt] = (f32x4){0.f, 0.f, 0.f, 0.f};
      short8v b0 = *reinterpret_cast<const short8v*>(&Kl[nt * 16 + lr][lg * 8]);
      s[nt] = MFMA16(aq0, b0, s[nt]);
      short8v b1 = *reinterpret_cast<const short8v*>(&Kl[nt * 16 + lr][32 + lg * 8]);
      s[nt] = MFMA16(aq1, b1, s[nt]);
    }

    bool edge = (kt + 63 > q0 + wid * 16) || ((q0 - kt) + wid * 16 + 15 > W);
#pragma unroll
    for (int r = 0; r < 4; r++) {
      if (edge) {
        int t = q0 + wid * 16 + lg * 4 + r;
#pragma unroll
        for (int nt = 0; nt < 4; nt++) {
          int k = kt + nt * 16 + lr;
          float val = ((k <= t) && (t - k <= W)) ? s[nt][r] : -1e30f;
          Pl[wid][lg * 4 + r][nt * 16 + lr] = f2bf(exp2f(val - 12.f));
        }
      } else {
#pragma unroll
        for (int nt = 0; nt < 4; nt++)
          Pl[wid][lg * 4 + r][nt * 16 + lr] = f2bf(exp2f(s[nt][r] - 12.f));
      }
    }

    short8v ap0 = *reinterpret_cast<const short8v*>(&Pl[wid][lr][lg * 8]);
    short8v ap1 = *reinterpret_cast<const short8v*>(&Pl[wid][lr][32 + lg * 8]);
    f32x4 psum = (f32x4){0.f, 0.f, 0.f, 0.f};
    psum = MFMA16(ap0, vones, psum);
    psum = MFMA16(ap1, vones, psum);
#pragma unroll
    for (int dt = 0; dt < 4; dt++) {
      short8v v0 = *reinterpret_cast<const short8v*>(&Vt[dt * 16 + lr][lg * 8]);
      oacc[dt] = MFMA16(ap0, v0, oacc[dt]);
      short8v v1 = *reinterpret_cast<const short8v*>(&Vt[dt * 16 + lr][32 + lg * 8]);
      oacc[dt] = MFMA16(ap1, v1, oacc[dt]);
    }
#pragma unroll
    for (int r = 0; r < 4; r++) l_run[r] += psum[r];
  }

#pragma unroll
  for (int r = 0; r < 4; r++) {
    int t = q0 + wid * 16 + lg * 4 + r;
    float inv = 1.f / l_run[r];
#pragma unroll
    for (int dt = 0; dt < 4; dt++) {
      O[(((size_t)b * T + t) << 10) + (h << 6) + dt * 16 + lr] = f2bf(oacc[dt][r] * inv);
    }
  }
}

extern "C" void kernel_launch(void* const* d_in, const int* in_sizes, int n_in,
                              void* d_out, int out_size, void* d_ws, size_t ws_size,
                              hipStream_t stream) {
  (void)in_sizes; (void)n_in; (void)out_size; (void)ws_size;
  const float* x    = (const float*)d_in[0];
  const float* cosp = (const float*)d_in[1];
  const float* sinp = (const float*)d_in[2];
  const float* kvw  = (const float*)d_in[3];
  const float* pw   = (const float*)d_in[4];
  const int*   win  = (const int*)d_in[5];

  // ws layout (ws >= 256MB confirmed by harness 0xAA fill of 256MB):
  // 0-8    xbf            8-10  kvwbf        10-12 pwbf
  // 12-28  kvf p0 / outp0 28-44 kvf p1 / outp1
  // 44-52  kvbf           52-60 kvt          60-68 qbf      68-76 aout
  char* w = (char*)d_ws;
  u16*   xbf   = (u16*)(w);
  u16*   kvwbf = (u16*)(w + (8u << 20));
  u16*   pwbf  = (u16*)(w + (10u << 20));
  float* kvfp  = (float*)(w + (12u << 20));        // 2 partials, 16MB each
  float* outp  = (float*)(w + (12u << 20));        // reuse after kvf dead
  u16*   kvbf  = (u16*)(w + (44u << 20));
  u16*   kvt   = (u16*)(w + (52u << 20));
  u16*   qbf   = (u16*)(w + (60u << 20));
  u16*   aout  = (u16*)(w + (68u << 20));
  const size_t PART = (size_t)4096 * 1024;         // elems per partial

  cast2_f32_bf16<<<2048, 256, 0, stream>>>(kvw, kvwbf, pw, pwbf);

  // x cast + q = rmsnorm(rotary(x)) * 0.125*log2e (also emits xbf for GEMM1)
  rope_rms_x<<<16384, 256, 0, stream>>>(x, xbf, qbf, cosp, sinp, 0.18033688011112042f);

  // kv partials = x @ kv_w^T (split-K=2)
  gemm_bt<<<dim3(64, 8, 2), 256, 0, stream>>>(xbf, kvwbf, kvfp, 4096, 1024, 1024, 512);

  // kv = rmsnorm(rotary(p0+p1)) -> (B,H,T,D) and (B,H,D,T)
  rope_rms_kv<<<dim3(32, 32), 256, 0, stream>>>(kvfp, kvfp + PART, kvbf, kvt, cosp, sinp);

  // sliding-window attention -> (B,T,C) bf16
  attn_swa<<<1024, 256, 0, stream>>>(qbf, kvbf, kvt, aout, win);

  // out partials = attn_out @ proj_w^T (split-K=2), then sum
  gemm_bt<<<dim3(64, 8, 2), 256, 0, stream>>>(aout, pwbf, outp, 4096, 1024, 1024, 512);
  reduce2<<<4096, 256, 0, stream>>>(outp, outp + PART, (float*)d_out);
}

// Round 9
// 168.206 us; speedup vs baseline: 1.1445x; 1.1445x over previous
//
#include <hip/hip_runtime.h>
#include <hip/hip_bf16.h>

using u16 = unsigned short;
typedef __attribute__((ext_vector_type(8))) short short8v;
typedef __attribute__((ext_vector_type(4))) float f32x4;

#define MFMA16(a, b, c) __builtin_amdgcn_mfma_f32_16x16x32_bf16((a), (b), (c), 0, 0, 0)

#define GLOAD16(g, l) __builtin_amdgcn_global_load_lds(                       \
    (const __attribute__((address_space(1))) void*)(const void*)(g),          \
    (__attribute__((address_space(3))) void*)(void*)(l), 16, 0, 0)

static __device__ __forceinline__ u16 f2bf(float x) {
  __hip_bfloat16 h = __float2bfloat16(x);
  return __builtin_bit_cast(u16, h);
}
static __device__ __forceinline__ float bf2f(u16 v) {
  __hip_bfloat16 h = __builtin_bit_cast(__hip_bfloat16, v);
  return __bfloat162float(h);
}

// cast the two weight matrices (1M elems each)
__global__ __launch_bounds__(256) void cast2_f32_bf16(const float* __restrict__ a, u16* __restrict__ da,
                                                      const float* __restrict__ b, u16* __restrict__ db) {
  int bid = blockIdx.x;
  const float* s; u16* d; int i;
  if (bid < 1024) { s = a; d = da; i = bid; }
  else            { s = b; d = db; i = bid - 1024; }
  int idx = (i * 256 + threadIdx.x) * 4;
  float4 v = *reinterpret_cast<const float4*>(s + idx);
  ushort4 o;
  o.x = f2bf(v.x); o.y = f2bf(v.y); o.z = f2bf(v.z); o.w = f2bf(v.w);
  *reinterpret_cast<ushort4*>(d + idx) = o;
}

// C[M,N] = A[M,K] bf16 @ Bt[N,K]^T. BM=64 BN=128 BK=32, 4 waves (2x2).
// Depth-2 counted-vmcnt pipeline (T3+T4), 4 LDS buffers (r6-proven).
// L2-blocked XCD mapping (1D grid 512, M=4096 N=1024 fixed): XCD x = bid%8
// owns bm in [8x,8x+8) x all bn -> per-XCD: A-slice 1MB + B 2MB, L2-resident.
// BF16OUT: write C as bf16 (for kv; attn consumes bf16 anyway).
template <bool BF16OUT>
__global__ __launch_bounds__(256) void gemm_bt(const u16* __restrict__ A,
                                               const u16* __restrict__ Bt,
                                               void* __restrict__ Cv,
                                               int M, int N, int K) {
  __shared__ u16 As[4][64 * 32];
  __shared__ u16 Bs[4][128 * 32];
  int bid = blockIdx.x;
  int bm = (bid & 7) * 8 + (bid >> 6);   // bijective for grid 512
  int bn = (bid >> 3) & 7;
  int tid = threadIdx.x;
  int wid = tid >> 6, l = tid & 63, lr = l & 15, lg = l >> 4;
  int wr = wid >> 1, wc = wid & 1;

  int srow = l >> 2, scol = (l & 3) * 8;
  const u16* Ag  = A  + (size_t)(bm * 64 + wid * 16 + srow) * K + scol;
  const u16* Bg0 = Bt + (size_t)(bn * 128 + wid * 32 + srow) * K + scol;
  const u16* Bg1 = Bg0 + (size_t)16 * K;

  f32x4 acc[2][4];
#pragma unroll
  for (int m = 0; m < 2; m++)
#pragma unroll
    for (int n = 0; n < 4; n++) acc[m][n] = (f32x4){0.f, 0.f, 0.f, 0.f};

  const int NT = K >> 5;

#pragma unroll
  for (int t = 0; t < 2; t++) {
    GLOAD16(Ag + t * 32, &As[t][wid * 512]);
    GLOAD16(Bg0 + t * 32, &Bs[t][wid * 1024]);
    GLOAD16(Bg1 + t * 32, &Bs[t][wid * 1024 + 512]);
  }

  for (int t = 0; t < NT; t++) {
    int cur = t & 3;
    if (t + 2 < NT) {
      int nb = (t + 2) & 3;
      int ko = (t + 2) * 32;
      GLOAD16(Ag + ko, &As[nb][wid * 512]);
      GLOAD16(Bg0 + ko, &Bs[nb][wid * 1024]);
      GLOAD16(Bg1 + ko, &Bs[nb][wid * 1024 + 512]);
    }
    if (t + 2 < NT)      asm volatile("s_waitcnt vmcnt(6)" ::: "memory");
    else if (t + 1 < NT) asm volatile("s_waitcnt vmcnt(3)" ::: "memory");
    else                 asm volatile("s_waitcnt vmcnt(0)" ::: "memory");
    __builtin_amdgcn_s_barrier();

    short8v af[2], bfr[4];
#pragma unroll
    for (int m = 0; m < 2; m++)
      af[m] = *reinterpret_cast<const short8v*>(&As[cur][(wr * 32 + m * 16 + lr) * 32 + lg * 8]);
#pragma unroll
    for (int n = 0; n < 4; n++)
      bfr[n] = *reinterpret_cast<const short8v*>(&Bs[cur][(wc * 64 + n * 16 + lr) * 32 + lg * 8]);
    asm volatile("s_waitcnt lgkmcnt(0)" ::: "memory");
    __builtin_amdgcn_sched_barrier(0);  // pin MFMAs below the wait (rule #18)
    __builtin_amdgcn_s_setprio(1);
#pragma unroll
    for (int m = 0; m < 2; m++)
#pragma unroll
      for (int n = 0; n < 4; n++) acc[m][n] = MFMA16(af[m], bfr[n], acc[m][n]);
    __builtin_amdgcn_s_setprio(0);
  }

#pragma unroll
  for (int m = 0; m < 2; m++)
#pragma unroll
    for (int n = 0; n < 4; n++)
#pragma unroll
      for (int r = 0; r < 4; r++) {
        int row = bm * 64 + wr * 32 + m * 16 + lg * 4 + r;
        int col = bn * 128 + wc * 64 + n * 16 + lr;
        if constexpr (BF16OUT)
          ((u16*)Cv)[(size_t)row * N + col] = f2bf(acc[m][n][r]);
        else
          ((float*)Cv)[(size_t)row * N + col] = acc[m][n][r];
      }
}

// fused x cast + rotary + rms_norm for q: one wave per (b,t,h) row of 64.
// src x (B,T,H,D) fp32 -> xbf (same layout, bf16) AND q (B,H,T,D) bf16 scaled.
__global__ __launch_bounds__(256) void rope_rms_x(const float* __restrict__ src,
                                                  u16* __restrict__ xbf,
                                                  u16* __restrict__ qdst,
                                                  const float* __restrict__ cosp,
                                                  const float* __restrict__ sinp,
                                                  float scale) {
  int R = blockIdx.x * 4 + (threadIdx.x >> 6);  // R = (b*T + t)*H + h
  int l = threadIdx.x & 63;
  int h = R & 15;
  int bt = R >> 4;
  int t = bt & 2047, b = bt >> 11;

  float v = src[((size_t)R << 6) + l];
  xbf[((size_t)R << 6) + l] = f2bf(v);
  float p = __shfl_xor(v, 32);
  float c = cosp[(t << 5) + (l & 31)];
  float s = sinp[(t << 5) + (l & 31)];
  float r = v * c + ((l < 32) ? p * s : -p * s);
  float sq = r * r;
  sq += __shfl_xor(sq, 32);
  sq += __shfl_xor(sq, 16);
  sq += __shfl_xor(sq, 8);
  sq += __shfl_xor(sq, 4);
  sq += __shfl_xor(sq, 2);
  sq += __shfl_xor(sq, 1);
  float inv = rsqrtf(sq * (1.0f / 64.0f) + 1.1920928955078125e-07f) * scale;
  qdst[((((size_t)b * 16 + h) * 2048 + t) << 6) + l] = f2bf(r * inv);
}

// fused rotary + rms_norm for kv (bf16 input from GEMM1, (B,T,H,D) layout),
// writing BOTH (B,H,T,D) and transposed (B,H,D,T).
// grid (T/64, BH); 4 waves; wave w: t-rows w*16..+15.
__global__ __launch_bounds__(256) void rope_rms_kv(const u16* __restrict__ src,
                                                   u16* __restrict__ dst,
                                                   u16* __restrict__ dstT,
                                                   const float* __restrict__ cosp,
                                                   const float* __restrict__ sinp) {
  __shared__ u16 Ld[64][72];
  int t0 = blockIdx.x << 6;
  int bh = blockIdx.y;
  int b = bh >> 4, h = bh & 15;
  int tid = threadIdx.x;
  int w = tid >> 6, l = tid & 63;

  for (int i = 0; i < 16; i++) {
    int tt = w * 16 + i;
    int t = t0 + tt;
    size_t idx = ((((size_t)b * 2048 + t) * 16 + h) << 6) + l;
    float v = bf2f(src[idx]);
    float p = __shfl_xor(v, 32);
    float cl = cosp[(t << 5) + (l & 31)];
    float sl = sinp[(t << 5) + (l & 31)];
    float r = v * cl + ((l < 32) ? p * sl : -p * sl);
    float sq = r * r;
    sq += __shfl_xor(sq, 32);
    sq += __shfl_xor(sq, 16);
    sq += __shfl_xor(sq, 8);
    sq += __shfl_xor(sq, 4);
    sq += __shfl_xor(sq, 2);
    sq += __shfl_xor(sq, 1);
    float inv = rsqrtf(sq * (1.0f / 64.0f) + 1.1920928955078125e-07f);
    u16 val = f2bf(r * inv);
    dst[(((size_t)bh * 2048 + t) << 6) + l] = val;
    Ld[tt][l] = val;
  }
  __syncthreads();
#pragma unroll
  for (int i = 0; i < 2; i++) {
    int c = tid + i * 256, dr = c >> 3, sg = c & 7;
    short8v v;
#pragma unroll
    for (int j = 0; j < 8; j++) v[j] = (short)Ld[sg * 8 + j][dr];
    *reinterpret_cast<short8v*>(dstT + ((size_t)bh * 64 + dr) * 2048 + t0 + sg * 8) = v;
  }
}

// sliding-window flash attention. Q: (B,H,T,D) bf16 PRE-SCALED by 0.125*log2e;
// KV: (B,H,T,D); KVt: (B,H,D,T). O: (B,T,H*D) bf16.
// NO online max: |s| <= 11.7 (rms-normed rows), so p = exp2(s-12) <= 1 and the
// final division cancels the fixed offset -> numerically identical softmax.
__global__ __launch_bounds__(256) void attn_swa(const u16* __restrict__ Q,
                                                const u16* __restrict__ KV,
                                                const u16* __restrict__ KVt,
                                                u16* __restrict__ O,
                                                const int* __restrict__ winp) {
  const int T = 2048;
  int bid = blockIdx.x;
  int bh = bid & 31;
  int qi = 31 - (bid >> 5);
  int q0 = qi << 6;
  int b = bh >> 4, h = bh & 15;
  int W = *winp;
  int tid = threadIdx.x;
  int wid = tid >> 6, l = tid & 63, lr = l & 15, lg = l >> 4;

  __shared__ u16 Kl[64][72];
  __shared__ u16 Vt[64][72];
  __shared__ u16 Pl[4][16][72];

  const u16* Qb = Q + (((size_t)bh * T + q0 + wid * 16 + lr) << 6);
  short8v aq0 = *reinterpret_cast<const short8v*>(Qb + lg * 8);
  short8v aq1 = *reinterpret_cast<const short8v*>(Qb + 32 + lg * 8);

  const short one_bf = (short)0x3F80;
  short8v vones = {one_bf, one_bf, one_bf, one_bf, one_bf, one_bf, one_bf, one_bf};

  float l_run[4];
  f32x4 oacc[4];
#pragma unroll
  for (int r = 0; r < 4; r++) l_run[r] = 0.f;
#pragma unroll
  for (int dt = 0; dt < 4; dt++) oacc[dt] = (f32x4){0.f, 0.f, 0.f, 0.f};

  int lo = q0 - W;
  if (lo < 0) lo = 0;
  lo &= ~63;

  const u16* KVbh  = KV + (((size_t)bh * T) << 6);
  const u16* KVtbh = KVt + ((size_t)bh << 6) * T;
  int r8 = tid >> 3, sg = tid & 7;

  short8v vK0 = *reinterpret_cast<const short8v*>(KVbh + ((size_t)(lo + r8) << 6) + sg * 8);
  short8v vK1 = *reinterpret_cast<const short8v*>(KVbh + ((size_t)(lo + r8 + 32) << 6) + sg * 8);
  short8v vV0 = *reinterpret_cast<const short8v*>(KVtbh + (size_t)r8 * T + lo + sg * 8);
  short8v vV1 = *reinterpret_cast<const short8v*>(KVtbh + (size_t)(r8 + 32) * T + lo + sg * 8);

  for (int kt = lo; kt <= q0; kt += 64) {
    __syncthreads();
    *reinterpret_cast<short8v*>(&Kl[r8][sg * 8]) = vK0;
    *reinterpret_cast<short8v*>(&Kl[r8 + 32][sg * 8]) = vK1;
    *reinterpret_cast<short8v*>(&Vt[r8][sg * 8]) = vV0;
    *reinterpret_cast<short8v*>(&Vt[r8 + 32][sg * 8]) = vV1;
    __syncthreads();
    if (kt < q0) {
      vK0 = *reinterpret_cast<const short8v*>(KVbh + ((size_t)(kt + 64 + r8) << 6) + sg * 8);
      vK1 = *reinterpret_cast<const short8v*>(KVbh + ((size_t)(kt + 64 + r8 + 32) << 6) + sg * 8);
      vV0 = *reinterpret_cast<const short8v*>(KVtbh + (size_t)r8 * T + kt + 64 + sg * 8);
      vV1 = *reinterpret_cast<const short8v*>(KVtbh + (size_t)(r8 + 32) * T + kt + 64 + sg * 8);
    }

    f32x4 s[4];
#pragma unroll
    for (int nt = 0; nt < 4; nt++) {
      s[nt] = (f32x4){0.f, 0.f, 0.f, 0.f};
      short8v b0 = *reinterpret_cast<const short8v*>(&Kl[nt * 16 + lr][lg * 8]);
      s[nt] = MFMA16(aq0, b0, s[nt]);
      short8v b1 = *reinterpret_cast<const short8v*>(&Kl[nt * 16 + lr][32 + lg * 8]);
      s[nt] = MFMA16(aq1, b1, s[nt]);
    }

    bool edge = (kt + 63 > q0 + wid * 16) || ((q0 - kt) + wid * 16 + 15 > W);
#pragma unroll
    for (int r = 0; r < 4; r++) {
      if (edge) {
        int t = q0 + wid * 16 + lg * 4 + r;
#pragma unroll
        for (int nt = 0; nt < 4; nt++) {
          int k = kt + nt * 16 + lr;
          float val = ((k <= t) && (t - k <= W)) ? s[nt][r] : -1e30f;
          Pl[wid][lg * 4 + r][nt * 16 + lr] = f2bf(exp2f(val - 12.f));
        }
      } else {
#pragma unroll
        for (int nt = 0; nt < 4; nt++)
          Pl[wid][lg * 4 + r][nt * 16 + lr] = f2bf(exp2f(s[nt][r] - 12.f));
      }
    }

    short8v ap0 = *reinterpret_cast<const short8v*>(&Pl[wid][lr][lg * 8]);
    short8v ap1 = *reinterpret_cast<const short8v*>(&Pl[wid][lr][32 + lg * 8]);
    f32x4 psum = (f32x4){0.f, 0.f, 0.f, 0.f};
    psum = MFMA16(ap0, vones, psum);
    psum = MFMA16(ap1, vones, psum);
#pragma unroll
    for (int dt = 0; dt < 4; dt++) {
      short8v v0 = *reinterpret_cast<const short8v*>(&Vt[dt * 16 + lr][lg * 8]);
      oacc[dt] = MFMA16(ap0, v0, oacc[dt]);
      short8v v1 = *reinterpret_cast<const short8v*>(&Vt[dt * 16 + lr][32 + lg * 8]);
      oacc[dt] = MFMA16(ap1, v1, oacc[dt]);
    }
#pragma unroll
    for (int r = 0; r < 4; r++) l_run[r] += psum[r];
  }

#pragma unroll
  for (int r = 0; r < 4; r++) {
    int t = q0 + wid * 16 + lg * 4 + r;
    float inv = 1.f / l_run[r];
#pragma unroll
    for (int dt = 0; dt < 4; dt++) {
      O[(((size_t)b * T + t) << 10) + (h << 6) + dt * 16 + lr] = f2bf(oacc[dt][r] * inv);
    }
  }
}

extern "C" void kernel_launch(void* const* d_in, const int* in_sizes, int n_in,
                              void* d_out, int out_size, void* d_ws, size_t ws_size,
                              hipStream_t stream) {
  (void)in_sizes; (void)n_in; (void)out_size; (void)ws_size;
  const float* x    = (const float*)d_in[0];
  const float* cosp = (const float*)d_in[1];
  const float* sinp = (const float*)d_in[2];
  const float* kvw  = (const float*)d_in[3];
  const float* pw   = (const float*)d_in[4];
  const int*   win  = (const int*)d_in[5];

  // ws layout: 0-8 xbf | 8-10 kvwbf | 10-12 pwbf | 12-20 kvlin (bf16, BTHD)
  //            20-28 kvbf (BHTD) | 28-36 kvt (BHDT) | 36-44 qbf | 44-52 aout
  char* w = (char*)d_ws;
  u16* xbf   = (u16*)(w);
  u16* kvwbf = (u16*)(w + (8u << 20));
  u16* pwbf  = (u16*)(w + (10u << 20));
  u16* kvlin = (u16*)(w + (12u << 20));
  u16* kvbf  = (u16*)(w + (20u << 20));
  u16* kvt   = (u16*)(w + (28u << 20));
  u16* qbf   = (u16*)(w + (36u << 20));
  u16* aout  = (u16*)(w + (44u << 20));

  cast2_f32_bf16<<<2048, 256, 0, stream>>>(kvw, kvwbf, pw, pwbf);

  // x cast + q = rmsnorm(rotary(x)) * 0.125*log2e (also emits xbf for GEMM1)
  rope_rms_x<<<16384, 256, 0, stream>>>(x, xbf, qbf, cosp, sinp, 0.18033688011112042f);

  // kv = x @ kv_w^T  -> bf16 (B,T,H,D)
  gemm_bt<true><<<512, 256, 0, stream>>>(xbf, kvwbf, kvlin, 4096, 1024, 1024);

  // kv = rmsnorm(rotary(kv)) -> (B,H,T,D) and (B,H,D,T)
  rope_rms_kv<<<dim3(32, 32), 256, 0, stream>>>(kvlin, kvbf, kvt, cosp, sinp);

  // sliding-window attention -> (B,T,C) bf16
  attn_swa<<<1024, 256, 0, stream>>>(qbf, kvbf, kvt, aout, win);

  // out = attn_out @ proj_w^T -> fp32
  gemm_bt<false><<<512, 256, 0, stream>>>(aout, pwbf, d_out, 4096, 1024, 1024);
}